// Round 1
// baseline (347.587 us; speedup 1.0000x reference)
//
#include <hip/hip_runtime.h>

#define B_  16
#define N_  4096
#define M_  1024
#define C1_ 128
#define C2_ 256
#define K0_ 384   // C2 + C1
#define O1_ 256
#define O2_ 256

typedef _Float16 half4 __attribute__((ext_vector_type(4)));
typedef _Float16 half8 __attribute__((ext_vector_type(8)));
typedef float    f32x4 __attribute__((ext_vector_type(4)));

// ---------------------------------------------------------------------------
// K1: three_nn. One thread per query point; scalar (wave-uniform) reads of
// xyz2 stream through the scalar cache. Strict '<' insertion == top_k tie
// order (first index wins).
// ---------------------------------------------------------------------------
__global__ void three_nn_kernel(const float* __restrict__ xyz1,
                                const float* __restrict__ xyz2,
                                int* __restrict__ idxb, float* __restrict__ wb) {
    int b = blockIdx.y;
    int n = blockIdx.x * 256 + threadIdx.x;
    const float* q = xyz1 + (size_t)b * 3 * N_;
    float px = q[n], py = q[N_ + n], pz = q[2 * N_ + n];
    const float* p = xyz2 + (size_t)b * 3 * M_;
    float b0 = 1e30f, b1v = 1e30f, b2v = 1e30f;
    int i0 = 0, i1 = 0, i2 = 0;
    for (int m = 0; m < M_; ++m) {
        float dx = px - p[m];
        float dy = py - p[M_ + m];
        float dz = pz - p[2 * M_ + m];
        float d = fmaf(dz, dz, fmaf(dy, dy, dx * dx));
        if (d < b2v) {
            if (d < b1v) {
                b2v = b1v; i2 = i1;
                if (d < b0) { b1v = b0; i1 = i0; b0 = d; i0 = m; }
                else        { b1v = d;  i1 = m; }
            } else { b2v = d; i2 = m; }
        }
    }
    float d0 = fmaxf(sqrtf(fmaxf(b0,  1e-20f)), 1e-10f);
    float d1 = fmaxf(sqrtf(fmaxf(b1v, 1e-20f)), 1e-10f);
    float d2 = fmaxf(sqrtf(fmaxf(b2v, 1e-20f)), 1e-10f);
    float r0 = 1.f / d0, r1 = 1.f / d1, r2 = 1.f / d2;
    float s = r0 + r1 + r2;
    size_t j = ((size_t)b * N_ + n) * 3;
    idxb[j] = i0; idxb[j + 1] = i1; idxb[j + 2] = i2;
    wb[j] = r0 / s; wb[j + 1] = r1 / s; wb[j + 2] = r2 / s;
}

// ---------------------------------------------------------------------------
// Convert W1/W2 to fp16 (row-major (O,K) kept — that IS the fragment layout).
// ---------------------------------------------------------------------------
__global__ void convert_w_kernel(const float* __restrict__ W1, const float* __restrict__ W2,
                                 _Float16* __restrict__ W1h, _Float16* __restrict__ W2h) {
    int t = blockIdx.x * 256 + threadIdx.x;
    if (t < O1_ * K0_) W1h[t] = (_Float16)W1[t];
    if (t < O2_ * O1_) W2h[t] = (_Float16)W2[t];
}

// ---------------------------------------------------------------------------
// Generic (C,NP) fp32 -> (NP,C) fp16 transpose via 64x64 LDS tile.
// Used for points2 -> p2T (gather locality) and points1 -> X rows 256..383.
// ---------------------------------------------------------------------------
__global__ void transpose_f16_kernel(const float* __restrict__ in, _Float16* __restrict__ out,
                                     int NP, size_t in_bstride, size_t out_bstride,
                                     int out_rstride, int out_coff) {
    __shared__ float tile[64][65];
    int t = threadIdx.x;
    int nb = blockIdx.x * 64, cb = blockIdx.y * 64;
    const float* ib = in + blockIdx.z * in_bstride;
#pragma unroll
    for (int r = 0; r < 16; ++r) {
        int c = r * 4 + (t >> 6);
        tile[c][t & 63] = ib[(size_t)(cb + c) * NP + nb + (t & 63)];
    }
    __syncthreads();
    _Float16* ob = out + blockIdx.z * out_bstride;
#pragma unroll
    for (int pass = 0; pass < 2; ++pass) {
        int id = pass * 256 + t;
        int nl = id >> 3;
        int c8 = (id & 7) * 8;
        half8 v;
#pragma unroll
        for (int jj = 0; jj < 8; ++jj) v[jj] = (_Float16)tile[c8 + jj][nl];
        *(half8*)(ob + (size_t)(nb + nl) * out_rstride + out_coff + cb + c8) = v;
    }
}

// ---------------------------------------------------------------------------
// Interp: X[n][c] = sum_k w_k * p2T[idx_k][c], rows are contiguous fp16.
// One wave per query point, lane = 4 channels.
// ---------------------------------------------------------------------------
__global__ void interp_kernel(const _Float16* __restrict__ p2T, const int* __restrict__ idxb,
                              const float* __restrict__ wb, _Float16* __restrict__ X, int b0) {
    int wv = threadIdx.x >> 6, lane = threadIdx.x & 63;
    int bloc = blockIdx.y;
    int b = b0 + bloc;
    int n = blockIdx.x * 4 + wv;
    size_t j = ((size_t)b * N_ + n) * 3;
    int i0 = idxb[j], i1 = idxb[j + 1], i2 = idxb[j + 2];
    float w0 = wb[j], w1 = wb[j + 1], w2 = wb[j + 2];
    const _Float16* pb = p2T + (size_t)b * M_ * C2_;
    half4 g0 = *(const half4*)(pb + (size_t)i0 * C2_ + lane * 4);
    half4 g1 = *(const half4*)(pb + (size_t)i1 * C2_ + lane * 4);
    half4 g2 = *(const half4*)(pb + (size_t)i2 * C2_ + lane * 4);
    half4 o;
#pragma unroll
    for (int jj = 0; jj < 4; ++jj) {
        float v = w0 * (float)g0[jj] + w1 * (float)g1[jj] + w2 * (float)g2[jj];
        o[jj] = (_Float16)v;
    }
    *(half4*)(X + ((size_t)bloc * N_ + n) * K0_ + lane * 4) = o;
}

// ---------------------------------------------------------------------------
// GEMM1: Y1[b][n][o] = relu(sum_k X[b][n][k] * W1[o][k] + b1[o]), fp16 MFMA.
// D = A(X: n x k) * B(W1^T: k x o). All fragments are direct 16B global loads.
// Wave: 2 n-frags x 16 o-frags (full O=256); block: 4 waves -> 128 n.
// ---------------------------------------------------------------------------
__global__ __launch_bounds__(256, 2)
void gemm1_kernel(const _Float16* __restrict__ X, const _Float16* __restrict__ W1h,
                  const float* __restrict__ b1, _Float16* __restrict__ Y1) {
    int wv = threadIdx.x >> 6, lane = threadIdx.x & 63;
    int lr = lane & 15, lh = lane >> 4;
    int bloc = blockIdx.y;
    int n0 = blockIdx.x * 128 + wv * 32;
    const _Float16* a0p = X + ((size_t)bloc * N_ + n0 + lr) * K0_ + lh * 8;
    const _Float16* a1p = a0p + 16 * K0_;
    const _Float16* bp  = W1h + (size_t)lr * K0_ + lh * 8;

    f32x4 acc[2][16];
    f32x4 z = {0.f, 0.f, 0.f, 0.f};
#pragma unroll
    for (int i = 0; i < 2; ++i)
#pragma unroll
        for (int j = 0; j < 16; ++j) acc[i][j] = z;

    for (int k = 0; k < K0_; k += 32) {
        half8 a0 = *(const half8*)(a0p + k);
        half8 a1 = *(const half8*)(a1p + k);
#pragma unroll
        for (int of = 0; of < 16; ++of) {
            half8 bb = *(const half8*)(bp + of * 16 * K0_ + k);
            acc[0][of] = __builtin_amdgcn_mfma_f32_16x16x32_f16(a0, bb, acc[0][of], 0, 0, 0);
            acc[1][of] = __builtin_amdgcn_mfma_f32_16x16x32_f16(a1, bb, acc[1][of], 0, 0, 0);
        }
    }

    _Float16* yb = Y1 + ((size_t)bloc * N_) * O1_;
#pragma unroll
    for (int of = 0; of < 16; ++of) {
        float bias = b1[of * 16 + lr];
#pragma unroll
        for (int nf = 0; nf < 2; ++nf) {
            int nbase = n0 + nf * 16 + lh * 4;
#pragma unroll
            for (int r = 0; r < 4; ++r) {
                float v = acc[nf][of][r] + bias;
                yb[(size_t)(nbase + r) * O1_ + of * 16 + lr] = (_Float16)fmaxf(v, 0.f);
            }
        }
    }
}

// ---------------------------------------------------------------------------
// GEMM2: out[b][o2][n] = relu(sum_k W2[o2][k] * Y1[b][n][k] + b2[o2]).
// D = A(W2: o2 x k) * B(Y1^T: k x n) so D's columns are n -> output layout
// (B, O, N) falls out naturally. Wave: 4 o2-frags x 8 n-frags.
// ---------------------------------------------------------------------------
__global__ __launch_bounds__(256, 2)
void gemm2_kernel(const _Float16* __restrict__ Y1, const _Float16* __restrict__ W2h,
                  const float* __restrict__ b2, float* __restrict__ out, int b0) {
    int wv = threadIdx.x >> 6, lane = threadIdx.x & 63;
    int lr = lane & 15, lh = lane >> 4;
    int bloc = blockIdx.y;
    int b = b0 + bloc;
    int n0 = blockIdx.x * 128;
    int o2b = wv * 64;
    const _Float16* ap = W2h + (size_t)(o2b + lr) * O1_ + lh * 8;
    const _Float16* bp = Y1 + ((size_t)bloc * N_ + n0 + lr) * O1_ + lh * 8;

    f32x4 acc[4][8];
    f32x4 z = {0.f, 0.f, 0.f, 0.f};
#pragma unroll
    for (int i = 0; i < 4; ++i)
#pragma unroll
        for (int j = 0; j < 8; ++j) acc[i][j] = z;

    for (int k = 0; k < O1_; k += 32) {
        half8 av[4];
#pragma unroll
        for (int of = 0; of < 4; ++of) av[of] = *(const half8*)(ap + of * 16 * O1_ + k);
#pragma unroll
        for (int nf = 0; nf < 8; ++nf) {
            half8 bb = *(const half8*)(bp + (size_t)nf * 16 * O1_ + k);
#pragma unroll
            for (int of = 0; of < 4; ++of)
                acc[of][nf] = __builtin_amdgcn_mfma_f32_16x16x32_f16(av[of], bb, acc[of][nf], 0, 0, 0);
        }
    }

    float* ob = out + (size_t)b * O2_ * N_;
#pragma unroll
    for (int of = 0; of < 4; ++of) {
#pragma unroll
        for (int r = 0; r < 4; ++r) {
            int o2 = o2b + of * 16 + lh * 4 + r;
            float bias = b2[o2];
#pragma unroll
            for (int nf = 0; nf < 8; ++nf) {
                ob[(size_t)o2 * N_ + n0 + nf * 16 + lr] = fmaxf(acc[of][nf][r] + bias, 0.f);
            }
        }
    }
}

// ---------------------------------------------------------------------------
extern "C" void kernel_launch(void* const* d_in, const int* in_sizes, int n_in,
                              void* d_out, int out_size, void* d_ws, size_t ws_size,
                              hipStream_t stream) {
    const float* xyz1    = (const float*)d_in[0];
    const float* xyz2    = (const float*)d_in[1];
    const float* points1 = (const float*)d_in[2];
    const float* points2 = (const float*)d_in[3];
    const float* W1      = (const float*)d_in[4];
    const float* b1      = (const float*)d_in[5];
    const float* W2      = (const float*)d_in[6];
    const float* b2      = (const float*)d_in[7];
    float* out = (float*)d_out;

    char* p = (char*)d_ws;
    auto alloc = [&](size_t bytes) -> char* {
        char* r = p;
        p += (bytes + 255) & ~(size_t)255;
        return r;
    };
    _Float16* W1h  = (_Float16*)alloc((size_t)O1_ * K0_ * 2);
    _Float16* W2h  = (_Float16*)alloc((size_t)O2_ * O1_ * 2);
    int*      idxb = (int*)alloc((size_t)B_ * N_ * 3 * 4);
    float*    wb   = (float*)alloc((size_t)B_ * N_ * 3 * 4);
    _Float16* p2T  = (_Float16*)alloc((size_t)B_ * M_ * C2_ * 2);
    size_t fixed = (size_t)(p - (char*)d_ws);
    size_t per_b = (size_t)N_ * K0_ * 2 + (size_t)N_ * O1_ * 2;
    int G = (ws_size > fixed) ? (int)((ws_size - fixed) / per_b) : 1;
    if (G > B_) G = B_;
    if (G < 1) G = 1;
    _Float16* Xbuf = (_Float16*)alloc((size_t)G * N_ * K0_ * 2);
    _Float16* Y1   = (_Float16*)alloc((size_t)G * N_ * O1_ * 2);

    convert_w_kernel<<<dim3((O1_ * K0_ + 255) / 256), 256, 0, stream>>>(W1, W2, W1h, W2h);
    three_nn_kernel<<<dim3(N_ / 256, B_), 256, 0, stream>>>(xyz1, xyz2, idxb, wb);
    // points2 (B,C2,M) fp32 -> p2T (B,M,C2) fp16
    transpose_f16_kernel<<<dim3(M_ / 64, C2_ / 64, B_), 256, 0, stream>>>(
        points2, p2T, M_, (size_t)C2_ * M_, (size_t)M_ * C2_, C2_, 0);

    for (int b0 = 0; b0 < B_; b0 += G) {
        int gc = (B_ - b0 < G) ? (B_ - b0) : G;
        interp_kernel<<<dim3(N_ / 4, gc), 256, 0, stream>>>(p2T, idxb, wb, Xbuf, b0);
        // points1 (C1,N) fp32 -> X rows 256..383 fp16
        transpose_f16_kernel<<<dim3(N_ / 64, C1_ / 64, gc), 256, 0, stream>>>(
            points1 + (size_t)b0 * C1_ * N_, Xbuf, N_,
            (size_t)C1_ * N_, (size_t)N_ * K0_, K0_, C2_);
        gemm1_kernel<<<dim3(N_ / 128, gc), 256, 0, stream>>>(Xbuf, W1h, b1, Y1);
        gemm2_kernel<<<dim3(N_ / 128, gc), 256, 0, stream>>>(Y1, W2h, b2, out, b0);
    }
}

// Round 3
// 202.483 us; speedup vs baseline: 1.7166x; 1.7166x over previous
//
#include <hip/hip_runtime.h>

#define B_  16
#define N_  4096
#define M_  1024
#define C1_ 128
#define C2_ 256
#define K0_ 384   // C2 + C1
#define O1_ 256
#define O2_ 256

typedef _Float16 half4  __attribute__((ext_vector_type(4)));
typedef _Float16 half8  __attribute__((ext_vector_type(8)));
typedef float    f32x4  __attribute__((ext_vector_type(4)));

// ---------------------------------------------------------------------------
// three_nn v3: LDS-staged xyz2 as {x,y,z,|p|^2}, 4 threads/query (256 pts
// each). EXACT fp32 distances (no key-packing quantization — that flipped
// ~1-3% of 3rd/4th neighbors in v2). Sorted-insert: values via fmin + 2x
// v_med3_f32, indices via cmp/cndmask off the OLD keys. Strict '<' == top_k
// tie order. Butterfly merge of (dist,idx) triples via shfl_xor.
// d_rel = |p|^2 - 2 p.q (monotone in d^2; |q|^2 added back at the end).
// ---------------------------------------------------------------------------
__global__ __launch_bounds__(256)
void three_nn_kernel(const float* __restrict__ xyz1, const float* __restrict__ xyz2,
                     int* __restrict__ idxb, float* __restrict__ wb) {
    __shared__ float pts[4 * 1028];   // 4 chunks x 256 pts x 4 floats (+4 pad)
    int b = blockIdx.y;
    int t = threadIdx.x;
    {
        const float* src = xyz2 + (size_t)b * 3 * M_;
        int m0 = t * 4;
        f32x4 xv = *(const f32x4*)(src + m0);
        f32x4 yv = *(const f32x4*)(src + M_ + m0);
        f32x4 zv = *(const f32x4*)(src + 2 * M_ + m0);
        float* dst = pts + (t >> 6) * 1028 + (m0 & 255) * 4;
#pragma unroll
        for (int jj = 0; jj < 4; ++jj) {
            f32x4 o = {xv[jj], yv[jj], zv[jj],
                       fmaf(xv[jj], xv[jj], fmaf(yv[jj], yv[jj], zv[jj] * zv[jj]))};
            *(f32x4*)(dst + jj * 4) = o;
        }
    }
    __syncthreads();
    int lane = t & 63;
    int c = lane & 3;                       // chunk
    int q = ((t >> 6) << 4) + (lane >> 2);  // query within block 0..63
    int n = blockIdx.x * 64 + q;
    const float* qp = xyz1 + (size_t)b * 3 * N_;
    float px = qp[n], py = qp[N_ + n], pz = qp[2 * N_ + n];
    float px2 = -2.f * px, py2 = -2.f * py, pz2 = -2.f * pz;
    const float* base = pts + c * 1028;
    float b0 = 1e30f, b1v = 1e30f, b2v = 1e30f;
    int i0 = 0, i1 = 0, i2 = 0;
    int mb = c * 256;
#pragma unroll 4
    for (int i = 0; i < 256; ++i) {
        f32x4 pv = *(const f32x4*)(base + i * 4);
        float d = fmaf(pv[0], px2, fmaf(pv[1], py2, fmaf(pv[2], pz2, pv[3])));
        int m = mb + i;
        bool c0 = d < b0, c1 = d < b1v, c2 = d < b2v;
        float nb1 = __builtin_amdgcn_fmed3f(d, b0, b1v);
        float nb2 = __builtin_amdgcn_fmed3f(d, b1v, b2v);
        i2 = c1 ? i1 : (c2 ? m : i2);
        i1 = c0 ? i0 : (c1 ? m : i1);
        i0 = c0 ? m : i0;
        b0 = fminf(b0, d);
        b1v = nb1; b2v = nb2;
    }
    // merge sorted (dist,idx) triples across the 4 chunk-lanes of each query
#pragma unroll
    for (int st = 1; st <= 2; st <<= 1) {
        float d0 = __shfl_xor(b0, st, 64);  int j0 = __shfl_xor(i0, st, 64);
        float d1 = __shfl_xor(b1v, st, 64); int j1 = __shfl_xor(i1, st, 64);
        float d2 = __shfl_xor(b2v, st, 64); int j2 = __shfl_xor(i2, st, 64);
#pragma unroll
        for (int e = 0; e < 3; ++e) {
            float d = (e == 0) ? d0 : (e == 1) ? d1 : d2;
            int   m = (e == 0) ? j0 : (e == 1) ? j1 : j2;
            bool c0 = d < b0, c1 = d < b1v, c2 = d < b2v;
            float nb1 = __builtin_amdgcn_fmed3f(d, b0, b1v);
            float nb2 = __builtin_amdgcn_fmed3f(d, b1v, b2v);
            i2 = c1 ? i1 : (c2 ? m : i2);
            i1 = c0 ? i0 : (c1 ? m : i1);
            i0 = c0 ? m : i0;
            b0 = fminf(b0, d);
            b1v = nb1; b2v = nb2;
        }
    }
    if (c == 0) {
        float sq1 = fmaf(px, px, fmaf(py, py, pz * pz));
        float e0 = fmaxf(sqrtf(fmaxf(b0 + sq1, 1e-20f)), 1e-10f);
        float e1 = fmaxf(sqrtf(fmaxf(b1v + sq1, 1e-20f)), 1e-10f);
        float e2 = fmaxf(sqrtf(fmaxf(b2v + sq1, 1e-20f)), 1e-10f);
        float r0 = 1.f / e0, r1 = 1.f / e1, r2 = 1.f / e2;
        float s = r0 + r1 + r2;
        size_t j = ((size_t)b * N_ + n) * 3;
        idxb[j] = i0; idxb[j + 1] = i1; idxb[j + 2] = i2;
        wb[j] = r0 / s; wb[j + 1] = r1 / s; wb[j + 2] = r2 / s;
    }
}

// ---------------------------------------------------------------------------
// W1/W2 fp32 -> fp16 (row-major (O,K) kept: that IS the A-fragment layout).
// ---------------------------------------------------------------------------
__global__ __launch_bounds__(256)
void convert_w_kernel(const float* __restrict__ W1, const float* __restrict__ W2,
                      _Float16* __restrict__ W1h, _Float16* __restrict__ W2h) {
    int t = blockIdx.x * 256 + threadIdx.x;
    if (t < O1_ * K0_) W1h[t] = (_Float16)W1[t];
    if (t < O2_ * O1_) W2h[t] = (_Float16)W2[t];
}

// ---------------------------------------------------------------------------
// points2 (B,C2,M) fp32 -> p2T (B,M,C2) fp16 via 64x64 LDS tile.
// ---------------------------------------------------------------------------
__global__ __launch_bounds__(256)
void transpose_f16_kernel(const float* __restrict__ in, _Float16* __restrict__ out) {
    __shared__ float tile[64][65];
    int t = threadIdx.x;
    int nb = blockIdx.x * 64, cb = blockIdx.y * 64;
    const float* ib = in + (size_t)blockIdx.z * C2_ * M_;
#pragma unroll
    for (int r = 0; r < 16; ++r) {
        int cc = r * 4 + (t >> 6);
        tile[cc][t & 63] = ib[(size_t)(cb + cc) * M_ + nb + (t & 63)];
    }
    __syncthreads();
    _Float16* ob = out + (size_t)blockIdx.z * M_ * C2_;
#pragma unroll
    for (int pass = 0; pass < 2; ++pass) {
        int id = pass * 256 + t;
        int nl = id >> 3;
        int c8 = (id & 7) * 8;
        half8 v;
#pragma unroll
        for (int jj = 0; jj < 8; ++jj) v[jj] = (_Float16)tile[c8 + jj][nl];
        *(half8*)(ob + (size_t)(nb + nl) * C2_ + cb + c8) = v;
    }
}

// ---------------------------------------------------------------------------
// Fused: interp (fp32 accumulate, round once — round-1 numerics) + concat
// points1 + GEMM1(relu) -> swizzled LDS Y1 tile -> GEMM2(relu) -> out.
// Block: 128 n x one batch, 4 waves. D = W * X^T orientation so per-lane D
// rows are consecutive o -> half4 ds_write; phase-2 B-frags are swizzled
// conflict-free ds_read_b128.
// ---------------------------------------------------------------------------
__global__ __launch_bounds__(256, 2)
void fused_mlp_kernel(const _Float16* __restrict__ p2T, const int* __restrict__ idxb,
                      const float* __restrict__ wb, const float* __restrict__ points1,
                      const _Float16* __restrict__ W1h, const float* __restrict__ b1,
                      const _Float16* __restrict__ W2h, const float* __restrict__ b2,
                      float* __restrict__ out) {
    __shared__ _Float16 Y1s[128 * 256];   // 64 KB: row n*512B + o*2B, XOR-swizzled
    char* ybase = (char*)Y1s;
    int b = blockIdx.y;
    int n0b = blockIdx.x * 128;
    int t = threadIdx.x, lane = t & 63, wv = t >> 6;
    int lr = lane & 15, lh = lane >> 4;
    int wvn = wv >> 1, wvo = wv & 1;
    int swz = (lr & 7) << 4;

    // per-row interp params (4 B-frag rows per lane), weights kept fp32
    int ia[4], ib_[4], ic[4];
    float wa[4], wbv[4], wcv[4];
    const _Float16* p2b = p2T + (size_t)b * M_ * C2_;
#pragma unroll
    for (int nf = 0; nf < 4; ++nf) {
        int n = n0b + wvn * 64 + nf * 16 + lr;
        size_t j = ((size_t)b * N_ + n) * 3;
        ia[nf] = idxb[j]; ib_[nf] = idxb[j + 1]; ic[nf] = idxb[j + 2];
        wa[nf] = wb[j]; wbv[nf] = wb[j + 1]; wcv[nf] = wb[j + 2];
    }

    // ---- phase 1: Y1 = relu(W1 * X^T + b1), wave tile 128o x 64n ----
    f32x4 acc[8][4];
#pragma unroll
    for (int of = 0; of < 8; ++of) {
        int o = wvo * 128 + of * 16 + lh * 4;
        f32x4 bv = {b1[o], b1[o + 1], b1[o + 2], b1[o + 3]};
#pragma unroll
        for (int nf = 0; nf < 4; ++nf) acc[of][nf] = bv;
    }
    const _Float16* w1p = W1h + (size_t)(wvo * 128 + lr) * K0_ + lh * 8;

    for (int k0 = 0; k0 < 256; k0 += 32) {      // interpolated-points2 K range
        half8 bf[4];
#pragma unroll
        for (int nf = 0; nf < 4; ++nf) {
            const _Float16* g0 = p2b + (size_t)ia[nf]  * C2_ + k0 + lh * 8;
            const _Float16* g1 = p2b + (size_t)ib_[nf] * C2_ + k0 + lh * 8;
            const _Float16* g2 = p2b + (size_t)ic[nf]  * C2_ + k0 + lh * 8;
            half8 va = *(const half8*)g0, vb = *(const half8*)g1, vc = *(const half8*)g2;
#pragma unroll
            for (int jj = 0; jj < 8; ++jj) {
                float v = wa[nf] * (float)va[jj] + wbv[nf] * (float)vb[jj]
                        + wcv[nf] * (float)vc[jj];
                bf[nf][jj] = (_Float16)v;
            }
        }
#pragma unroll
        for (int of = 0; of < 8; ++of) {
            half8 af = *(const half8*)(w1p + (size_t)of * 16 * K0_ + k0);
#pragma unroll
            for (int nf = 0; nf < 4; ++nf)
                acc[of][nf] = __builtin_amdgcn_mfma_f32_16x16x32_f16(af, bf[nf], acc[of][nf], 0, 0, 0);
        }
    }
    for (int k0 = 0; k0 < 128; k0 += 32) {      // points1 K range (strided reads)
        half8 bf[4];
#pragma unroll
        for (int nf = 0; nf < 4; ++nf) {
            int n = n0b + wvn * 64 + nf * 16 + lr;
            const float* pp = points1 + ((size_t)b * C1_ + k0 + lh * 8) * N_ + n;
#pragma unroll
            for (int jj = 0; jj < 8; ++jj) bf[nf][jj] = (_Float16)pp[(size_t)jj * N_];
        }
#pragma unroll
        for (int of = 0; of < 8; ++of) {
            half8 af = *(const half8*)(w1p + (size_t)of * 16 * K0_ + 256 + k0);
#pragma unroll
            for (int nf = 0; nf < 4; ++nf)
                acc[of][nf] = __builtin_amdgcn_mfma_f32_16x16x32_f16(af, bf[nf], acc[of][nf], 0, 0, 0);
        }
    }
    // epilogue 1: relu -> fp16 -> swizzled LDS (4 consecutive o per write)
#pragma unroll
    for (int of = 0; of < 8; ++of) {
#pragma unroll
        for (int nf = 0; nf < 4; ++nf) {
            int nloc = wvn * 64 + nf * 16 + lr;
            int obyte = (wvo * 128 + of * 16 + lh * 4) * 2;
            half4 h;
#pragma unroll
            for (int r = 0; r < 4; ++r) h[r] = (_Float16)fmaxf(acc[of][nf][r], 0.f);
            *(half4*)(ybase + ((nloc * 512 + obyte) ^ swz)) = h;
        }
    }
    __syncthreads();

    // ---- phase 2: out = relu(W2 * Y1^T + b2), wave tile 64o2 x 128n ----
    f32x4 acc2[4][8];
    int o2b = wv * 64;
#pragma unroll
    for (int of = 0; of < 4; ++of) {
        int o = o2b + of * 16 + lh * 4;
        f32x4 bv = {b2[o], b2[o + 1], b2[o + 2], b2[o + 3]};
#pragma unroll
        for (int nf = 0; nf < 8; ++nf) acc2[of][nf] = bv;
    }
    const _Float16* w2p = W2h + (size_t)(o2b + lr) * O1_ + lh * 8;
    for (int k0 = 0; k0 < 256; k0 += 32) {
        half8 av[4];
#pragma unroll
        for (int of = 0; of < 4; ++of) av[of] = *(const half8*)(w2p + (size_t)of * 16 * O1_ + k0);
#pragma unroll
        for (int nf = 0; nf < 8; ++nf) {
            half8 bb = *(const half8*)(ybase + ((((nf * 16 + lr) * 512) + k0 * 2 + lh * 16) ^ swz));
#pragma unroll
            for (int of = 0; of < 4; ++of)
                acc2[of][nf] = __builtin_amdgcn_mfma_f32_16x16x32_f16(av[of], bb, acc2[of][nf], 0, 0, 0);
        }
    }
    float* ob = out + (size_t)b * O2_ * N_;
#pragma unroll
    for (int of = 0; of < 4; ++of) {
#pragma unroll
        for (int r = 0; r < 4; ++r) {
            int o2 = o2b + of * 16 + lh * 4 + r;
#pragma unroll
            for (int nf = 0; nf < 8; ++nf)
                ob[(size_t)o2 * N_ + n0b + nf * 16 + lr] = fmaxf(acc2[of][nf][r], 0.f);
        }
    }
}

// ---------------------------------------------------------------------------
extern "C" void kernel_launch(void* const* d_in, const int* in_sizes, int n_in,
                              void* d_out, int out_size, void* d_ws, size_t ws_size,
                              hipStream_t stream) {
    const float* xyz1    = (const float*)d_in[0];
    const float* xyz2    = (const float*)d_in[1];
    const float* points1 = (const float*)d_in[2];
    const float* points2 = (const float*)d_in[3];
    const float* W1      = (const float*)d_in[4];
    const float* b1      = (const float*)d_in[5];
    const float* W2      = (const float*)d_in[6];
    const float* b2      = (const float*)d_in[7];
    float* out = (float*)d_out;

    char* p = (char*)d_ws;
    auto alloc = [&](size_t bytes) -> char* {
        char* r = p;
        p += (bytes + 255) & ~(size_t)255;
        return r;
    };
    _Float16* W1h  = (_Float16*)alloc((size_t)O1_ * K0_ * 2);
    _Float16* W2h  = (_Float16*)alloc((size_t)O2_ * O1_ * 2);
    int*      idxb = (int*)alloc((size_t)B_ * N_ * 3 * 4);
    float*    wbuf = (float*)alloc((size_t)B_ * N_ * 3 * 4);
    _Float16* p2T  = (_Float16*)alloc((size_t)B_ * M_ * C2_ * 2);
    (void)ws_size;

    convert_w_kernel<<<dim3((O1_ * K0_ + 255) / 256), 256, 0, stream>>>(W1, W2, W1h, W2h);
    three_nn_kernel<<<dim3(N_ / 64, B_), 256, 0, stream>>>(xyz1, xyz2, idxb, wbuf);
    transpose_f16_kernel<<<dim3(M_ / 64, C2_ / 64, B_), 256, 0, stream>>>(points2, p2T);
    fused_mlp_kernel<<<dim3(N_ / 128, B_), 256, 0, stream>>>(
        p2T, idxb, wbuf, points1, W1h, b1, W2h, b2, out);
}